// Round 3
// baseline (93.187 us; speedup 1.0000x reference)
//
#include <hip/hip_runtime.h>
#include <math.h>

// Problem constants (from reference setup_inputs)
constexpr int B = 8, N = 2048, H = 512, M = 96, S = 16;
constexpr int E = 256, D = 64, R = 5, MAXD = 600;
constexpr int NZ = 64;            // n-splits for sent max partial
constexpr int NCHUNK = N / NZ;    // 32
constexpr int MT = 8;             // mentions per block in gemm kernel
constexpr int HC = 4;             // h-chunks in gemm kernel
constexpr int HCHUNK = H / HC;    // 128
constexpr float NEG_INF = -1e10f;

// ---------------------------------------------------------------------------
// K1a: partial max over token axis.  grid (B, NZ), block 128 (thread = float4 of H)
__global__ void k_sent_partial(const float* __restrict__ node, float* __restrict__ part) {
    int t = threadIdx.x;          // float4 index, 128 covers H=512
    int b = blockIdx.x;
    int z = blockIdx.y;
    const float4* p = reinterpret_cast<const float4*>(node + ((size_t)b * N + (size_t)z * NCHUNK) * H) + t;
    float4 mx = p[0];
    #pragma unroll 8
    for (int n = 1; n < NCHUNK; ++n) {
        float4 v = p[(size_t)n * (H / 4)];
        mx.x = fmaxf(mx.x, v.x); mx.y = fmaxf(mx.y, v.y);
        mx.z = fmaxf(mx.z, v.z); mx.w = fmaxf(mx.w, v.w);
    }
    reinterpret_cast<float4*>(part + ((size_t)z * B + b) * H)[t] = mx;
}

// ---------------------------------------------------------------------------
// K1b: finish sent max + project onto W_score sent rows.  grid (B), block 256
__global__ void k_sent_score(const float* __restrict__ part, const float* __restrict__ Wsc,
                             const float* __restrict__ bsc, float* __restrict__ sS) {
    __shared__ float sent[H];
    __shared__ float red[R][4];
    int b = blockIdx.x;
    int t = threadIdx.x;
    for (int h = t; h < H; h += 256) {
        float mx = -INFINITY;
        for (int z = 0; z < NZ; ++z) mx = fmaxf(mx, part[((size_t)z * B + b) * H + h]);
        sent[h] = mx;
    }
    __syncthreads();
    float acc[R] = {0.f, 0.f, 0.f, 0.f, 0.f};
    for (int h = t; h < H; h += 256) {
        float v = sent[h];
        const float* w = Wsc + (size_t)(2 * E + D + h) * R;
        #pragma unroll
        for (int r = 0; r < R; ++r) acc[r] += v * w[r];
    }
    int wave = t >> 6, lane = t & 63;
    #pragma unroll
    for (int r = 0; r < R; ++r) {
        float v = acc[r];
        for (int off = 32; off; off >>= 1) v += __shfl_down(v, off, 64);
        if (lane == 0) red[r][wave] = v;
    }
    __syncthreads();
    if (t < R) {
        float v = red[t][0] + red[t][1] + red[t][2] + red[t][3];
        sS[b * R + t] = v + bsc[t];
    }
}

// ---------------------------------------------------------------------------
// K2a: span gather + masked-sum pool.  grid (M, B, 2), block 256 (thread = float2 of H)
// pooled[z][b][m][h]; validAB[z][b][m]
__global__ void k_pool(const float* __restrict__ node,
                       const int* __restrict__ cmap, const float* __restrict__ cmask,
                       const int* __restrict__ dmap, const float* __restrict__ dmask,
                       float* __restrict__ pooled, float* __restrict__ validAB) {
    int m = blockIdx.x, b = blockIdx.y, z = blockIdx.z;
    int t = threadIdx.x;
    const int*   map  = z ? dmap  : cmap;
    const float* mask = z ? dmask : cmask;

    __shared__ int   smap[S];
    __shared__ float smask[S];
    if (t < S) {
        size_t off = ((size_t)b * M + m) * S + t;
        smap[t]  = map[off];
        smask[t] = mask[off];
    }
    __syncthreads();

    float a0 = 0.f, a1 = 0.f;
    #pragma unroll
    for (int s = 0; s < S; ++s) {
        float mk = smask[s];
        const float2 v = reinterpret_cast<const float2*>(node + ((size_t)b * N + smap[s]) * H)[t];
        a0 += mk * v.x;
        a1 += mk * v.y;
    }
    size_t row = ((size_t)z * B + b) * M + m;
    reinterpret_cast<float2*>(pooled + row * H)[t] = make_float2(a0, a1);

    if (t == 0) {
        float ms = 0.f;
        #pragma unroll
        for (int s = 0; s < S; ++s) ms += smask[s];
        validAB[row] = (ms > 0.f) ? 1.f : 0.f;
    }
}

// ---------------------------------------------------------------------------
// K2b: partial GEMM dotp[hc][z][b][m][e] = pooled[.,hchunk] @ W[hchunk, e]
// grid (M/MT, B, 2*HC), block 256 (thread = e). Plain stores, no atomics.
__global__ void k_gemm_partial(const float* __restrict__ pooled,
                               const float* __restrict__ Wc, const float* __restrict__ Wd,
                               float* __restrict__ dotp) {
    int mg = blockIdx.x, b = blockIdx.y;
    int z  = blockIdx.z >> 2;
    int hc = blockIdx.z & 3;
    int t  = threadIdx.x;
    const float* W = z ? Wd : Wc;

    __shared__ float lp[MT][HCHUNK];   // 4 KB
    for (int i = t; i < MT * HCHUNK; i += 256) {
        int mi = i >> 7, hh = i & (HCHUNK - 1);
        lp[mi][hh] = pooled[(((size_t)z * B + b) * M + mg * MT + mi) * H + hc * HCHUNK + hh];
    }
    __syncthreads();

    float acc[MT];
    #pragma unroll
    for (int mi = 0; mi < MT; ++mi) acc[mi] = 0.f;

    const float* Wp = W + (size_t)(hc * HCHUNK) * E + t;
    for (int hh = 0; hh < HCHUNK; hh += 4) {
        float w0 = Wp[(size_t)(hh + 0) * E];
        float w1 = Wp[(size_t)(hh + 1) * E];
        float w2 = Wp[(size_t)(hh + 2) * E];
        float w3 = Wp[(size_t)(hh + 3) * E];
        #pragma unroll
        for (int mi = 0; mi < MT; ++mi) {
            const float4 pv = *reinterpret_cast<const float4*>(&lp[mi][hh]);
            acc[mi] += pv.x * w0 + pv.y * w1 + pv.z * w2 + pv.w * w3;
        }
    }
    #pragma unroll
    for (int mi = 0; mi < MT; ++mi) {
        size_t row = ((size_t)z * B + b) * M + mg * MT + mi;
        dotp[((size_t)hc * (2 * B * M) + row) * E + t] = acc[mi];
    }
}

// ---------------------------------------------------------------------------
// K2c: sum partials + tanh + rank-R projection.  grid (2*B*M), block 64
__global__ void k_tanh_proj(const float* __restrict__ dotp,
                            const float* __restrict__ bc, const float* __restrict__ bd,
                            const float* __restrict__ Wsc, float* __restrict__ sAB) {
    int rid = blockIdx.x;
    int z = rid / (B * M);
    int lane = threadIdx.x;
    const float* bias = z ? bd : bc;
    int scoff = z ? E : 0;

    float4 dv = make_float4(0.f, 0.f, 0.f, 0.f);
    #pragma unroll
    for (int hc = 0; hc < HC; ++hc) {
        float4 v = reinterpret_cast<const float4*>(dotp + ((size_t)hc * (2 * B * M) + rid) * E)[lane];
        dv.x += v.x; dv.y += v.y; dv.z += v.z; dv.w += v.w;
    }
    float4 bv = reinterpret_cast<const float4*>(bias)[lane];
    float v0 = tanhf(dv.x + bv.x);
    float v1 = tanhf(dv.y + bv.y);
    float v2 = tanhf(dv.z + bv.z);
    float v3 = tanhf(dv.w + bv.w);

    int e0 = scoff + lane * 4;
    float p[R];
    #pragma unroll
    for (int r = 0; r < R; ++r) {
        p[r] = v0 * Wsc[(size_t)(e0 + 0) * R + r] + v1 * Wsc[(size_t)(e0 + 1) * R + r]
             + v2 * Wsc[(size_t)(e0 + 2) * R + r] + v3 * Wsc[(size_t)(e0 + 3) * R + r];
    }
    #pragma unroll
    for (int r = 0; r < R; ++r) {
        for (int off = 32; off; off >>= 1) p[r] += __shfl_down(p[r], off, 64);
    }
    if (lane == 0) {
        #pragma unroll
        for (int r = 0; r < R; ++r) sAB[(size_t)rid * R + r] = p[r];
    }
}

// ---------------------------------------------------------------------------
// K3: distance-value score table.  grid (MAXD), block 64 (one wave)
__global__ void k_dist_table(const float* __restrict__ emb, const float* __restrict__ Wsc,
                             float* __restrict__ sD) {
    int d = blockIdx.x;
    int k = threadIdx.x;
    float v = emb[(size_t)d * D + k];
    #pragma unroll
    for (int r = 0; r < R; ++r) {
        float p = v * Wsc[(size_t)(2 * E + k) * R + r];
        for (int off = 32; off; off >>= 1) p += __shfl_down(p, off, 64);
        if (k == 0) sD[d * R + r] = p;
    }
}

// ---------------------------------------------------------------------------
// K4: pairwise max.  grid (B), block 256
__global__ void k_final(const int* __restrict__ distance,
                        const float* __restrict__ sAB, const float* __restrict__ validAB,
                        const float* __restrict__ sD, const float* __restrict__ sS,
                        float* __restrict__ out) {
    int b = blockIdx.x;
    int t = threadIdx.x;
    __shared__ float lA[M * R], lB[M * R];
    __shared__ float lD[MAXD * R];
    __shared__ float lvA[M], lvB[M];
    __shared__ float red[R][4];

    for (int i = t; i < M * R; i += 256) {
        lA[i] = sAB[(size_t)b * M * R + i];
        lB[i] = sAB[((size_t)(B + b)) * M * R + i];
    }
    for (int i = t; i < MAXD * R; i += 256) lD[i] = sD[i];
    for (int i = t; i < M; i += 256) {
        lvA[i] = validAB[(size_t)b * M + i];
        lvB[i] = validAB[((size_t)B + b) * M + i];
    }
    __syncthreads();

    float sSb[R];
    #pragma unroll
    for (int r = 0; r < R; ++r) sSb[r] = sS[b * R + r];
    float mx[R];
    #pragma unroll
    for (int r = 0; r < R; ++r) mx[r] = NEG_INF;

    for (int idx = t; idx < M * M; idx += 256) {
        int m = idx / M, n = idx % M;
        int dist = distance[((size_t)b * M + m) * M + n];
        bool valid = (lvA[m] > 0.f) && (lvB[n] > 0.f) && (dist >= 0 /*DIST_THRESH*/);
        if (valid) {
            #pragma unroll
            for (int r = 0; r < R; ++r) {
                float v = lA[m * R + r] + lB[n * R + r] + lD[dist * R + r] + sSb[r];
                mx[r] = fmaxf(mx[r], v);
            }
        }
    }
    int wave = t >> 6, lane = t & 63;
    #pragma unroll
    for (int r = 0; r < R; ++r) {
        float v = mx[r];
        for (int off = 32; off; off >>= 1) v = fmaxf(v, __shfl_down(v, off, 64));
        if (lane == 0) red[r][wave] = v;
    }
    __syncthreads();
    if (t < R) {
        float v = fmaxf(fmaxf(red[t][0], red[t][1]), fmaxf(red[t][2], red[t][3]));
        out[b * R + t] = v;
    }
}

// ---------------------------------------------------------------------------
extern "C" void kernel_launch(void* const* d_in, const int* in_sizes, int n_in,
                              void* d_out, int out_size, void* d_ws, size_t ws_size,
                              hipStream_t stream) {
    const float* node     = (const float*)d_in[0];
    const int*   cmap     = (const int*)  d_in[1];
    const float* cmask    = (const float*)d_in[2];
    const int*   dmap     = (const int*)  d_in[3];
    const float* dmask    = (const float*)d_in[4];
    const int*   distance = (const int*)  d_in[5];
    const float* Wc       = (const float*)d_in[6];
    const float* bc       = (const float*)d_in[7];
    const float* Wd       = (const float*)d_in[8];
    const float* bd       = (const float*)d_in[9];
    const float* Wsc      = (const float*)d_in[10];
    const float* bsc      = (const float*)d_in[11];
    const float* emb      = (const float*)d_in[12];
    float* out = (float*)d_out;

    // workspace layout (floats): total ~10.5 MB
    float* ws      = (float*)d_ws;
    float* part    = ws;                             // NZ*B*H      = 262144
    float* sS      = part + (size_t)NZ * B * H;      // B*R         = 40
    float* sAB     = sS + B * R;                     // 2*B*M*R     = 7680
    float* validAB = sAB + 2 * B * M * R;            // 2*B*M       = 1536
    float* sD      = validAB + 2 * B * M;            // MAXD*R      = 3000
    float* pooled  = sD + MAXD * R;                  // 2*B*M*H     = 786432
    float* dotp    = pooled + (size_t)2 * B * M * H; // HC*2*B*M*E  = 1572864

    hipLaunchKernelGGL(k_sent_partial, dim3(B, NZ), dim3(128), 0, stream, node, part);
    hipLaunchKernelGGL(k_pool, dim3(M, B, 2), dim3(256), 0, stream,
                       node, cmap, cmask, dmap, dmask, pooled, validAB);
    hipLaunchKernelGGL(k_sent_score, dim3(B), dim3(256), 0, stream, part, Wsc, bsc, sS);
    hipLaunchKernelGGL(k_gemm_partial, dim3(M / MT, B, 2 * HC), dim3(256), 0, stream,
                       pooled, Wc, Wd, dotp);
    hipLaunchKernelGGL(k_dist_table, dim3(MAXD), dim3(64), 0, stream, emb, Wsc, sD);
    hipLaunchKernelGGL(k_tanh_proj, dim3(2 * B * M), dim3(64), 0, stream, dotp, bc, bd, Wsc, sAB);
    hipLaunchKernelGGL(k_final, dim3(B), dim3(256), 0, stream, distance, sAB, validAB, sD, sS, out);
}

// Round 4
// 61.336 us; speedup vs baseline: 1.5193x; 1.5193x over previous
//
#include <hip/hip_runtime.h>
#include <math.h>

// Problem constants (from reference setup_inputs)
constexpr int B = 8, N = 2048, H = 512, M = 96, S = 16;
constexpr int E = 256, D = 64, R = 5, MAXD = 600;
constexpr int NZ = 64;            // n-splits for sent max partial
constexpr int NCHUNK = N / NZ;    // 32
constexpr int MT = 8;             // mentions per tile
constexpr int HC = 4;             // h-chunks in gemm
constexpr int HCHUNK = H / HC;    // 128
constexpr float NEG_INF = -1e10f;

constexpr int K1_SENT = 256;                    // sent-partial blocks (2 z each)
constexpr int K1_POOL = 2 * B * M;              // 1536 pool blocks
constexpr int K2_GEMM = (M / MT) * B * 2 * HC;  // 768
constexpr int K2_SENT = B;                      // 8
constexpr int K2_DIST = MAXD / 4;               // 150

__device__ inline void atomicMaxFloat(float* addr, float val) {
    int* ai = (int*)addr;
    int old = *ai;
    while (__int_as_float(old) < val) {
        int assumed = old;
        old = atomicCAS(ai, assumed, __float_as_int(val));
        if (old == assumed) break;
    }
}

// ---------------------------------------------------------------------------
// K1: fused sent-partial max (blocks [0,256)) + span gather/pool (blocks [256,1792))
__global__ void k1(const float* __restrict__ node,
                   const int* __restrict__ cmap, const float* __restrict__ cmask,
                   const int* __restrict__ dmap, const float* __restrict__ dmask,
                   float* __restrict__ part, float* __restrict__ pooled,
                   float* __restrict__ validAB) {
    int blk = blockIdx.x, t = threadIdx.x;
    __shared__ int   smap[S];
    __shared__ float smask[S];

    if (blk < K1_SENT) {
        // partial max over 32 tokens; block covers 2 z-chunks (t>>7)
        int b = blk >> 5;
        int z = ((blk & 31) << 1) + (t >> 7);
        int tt = t & 127;   // float4 index over H
        const float4* p = reinterpret_cast<const float4*>(
            node + ((size_t)b * N + (size_t)z * NCHUNK) * H) + tt;
        float4 mx = p[0];
        #pragma unroll
        for (int n = 1; n < NCHUNK; ++n) {
            float4 v = p[(size_t)n * (H / 4)];
            mx.x = fmaxf(mx.x, v.x); mx.y = fmaxf(mx.y, v.y);
            mx.z = fmaxf(mx.z, v.z); mx.w = fmaxf(mx.w, v.w);
        }
        reinterpret_cast<float4*>(part + ((size_t)z * B + b) * H)[tt] = mx;
    } else {
        int j = blk - K1_SENT;
        int m = j % M, b = (j / M) % B, z = j / (M * B);
        const int*   map  = z ? dmap  : cmap;
        const float* mask = z ? dmask : cmask;
        if (t < S) {
            size_t off = ((size_t)b * M + m) * S + t;
            smap[t]  = map[off];
            smask[t] = mask[off];
        }
        __syncthreads();
        float a0 = 0.f, a1 = 0.f;
        #pragma unroll
        for (int s = 0; s < S; ++s) {
            float mk = smask[s];
            const float2 v = reinterpret_cast<const float2*>(
                node + ((size_t)b * N + smap[s]) * H)[t];
            a0 += mk * v.x; a1 += mk * v.y;
        }
        size_t row = ((size_t)z * B + b) * M + m;
        reinterpret_cast<float2*>(pooled + row * H)[t] = make_float2(a0, a1);
        if (t == 0) {
            float ms = 0.f;
            #pragma unroll
            for (int s = 0; s < S; ++s) ms += smask[s];
            validAB[row] = (ms > 0.f) ? 1.f : 0.f;
        }
    }
}

// ---------------------------------------------------------------------------
// K2: fused partial GEMM (blocks [0,768)) + sent max-finish/score ([768,776))
//     + distance table ([776,926)) + out init (block 768)
__global__ void k2(const float* __restrict__ pooled,
                   const float* __restrict__ Wc, const float* __restrict__ Wd,
                   const float* __restrict__ part, const float* __restrict__ Wsc,
                   const float* __restrict__ bsc, const float* __restrict__ emb,
                   float* __restrict__ dotp, float* __restrict__ sS,
                   float* __restrict__ sD, float* __restrict__ out) {
    int blk = blockIdx.x, t = threadIdx.x;
    __shared__ float lp[MT][HCHUNK];   // 4 KB (gemm)
    __shared__ float sent[H];          // 2 KB (sent score)
    __shared__ float red[R][4];

    if (blk < K2_GEMM) {
        int mg  = blk % (M / MT);
        int b   = (blk / (M / MT)) % B;
        int zhc = blk / ((M / MT) * B);
        int z = zhc >> 2, hc = zhc & 3;
        const float* W = z ? Wd : Wc;

        for (int i = t; i < MT * HCHUNK; i += 256) {
            int mi = i >> 7, hh = i & (HCHUNK - 1);
            lp[mi][hh] = pooled[(((size_t)z * B + b) * M + mg * MT + mi) * H + hc * HCHUNK + hh];
        }
        __syncthreads();

        float acc[MT] = {};
        const float* Wp = W + (size_t)(hc * HCHUNK) * E + t;
        for (int hh = 0; hh < HCHUNK; hh += 4) {
            float w0 = Wp[(size_t)(hh + 0) * E];
            float w1 = Wp[(size_t)(hh + 1) * E];
            float w2 = Wp[(size_t)(hh + 2) * E];
            float w3 = Wp[(size_t)(hh + 3) * E];
            #pragma unroll
            for (int mi = 0; mi < MT; ++mi) {
                const float4 pv = *reinterpret_cast<const float4*>(&lp[mi][hh]);
                acc[mi] += pv.x * w0 + pv.y * w1 + pv.z * w2 + pv.w * w3;
            }
        }
        #pragma unroll
        for (int mi = 0; mi < MT; ++mi) {
            size_t row = ((size_t)z * B + b) * M + mg * MT + mi;
            dotp[((size_t)hc * (2 * B * M) + row) * E + t] = acc[mi];
        }
    } else if (blk < K2_GEMM + K2_SENT) {
        int b = blk - K2_GEMM;
        if (b == 0 && t < B * R) out[t] = NEG_INF;   // init for K4's atomicMax
        for (int h = t; h < H; h += 256) {
            float mx = -INFINITY;
            for (int z = 0; z < NZ; ++z) mx = fmaxf(mx, part[((size_t)z * B + b) * H + h]);
            sent[h] = mx;
        }
        __syncthreads();
        float acc[R] = {};
        for (int h = t; h < H; h += 256) {
            float v = sent[h];
            const float* w = Wsc + (size_t)(2 * E + D + h) * R;
            #pragma unroll
            for (int r = 0; r < R; ++r) acc[r] += v * w[r];
        }
        int wave = t >> 6, lane = t & 63;
        #pragma unroll
        for (int r = 0; r < R; ++r) {
            float v = acc[r];
            for (int off = 32; off; off >>= 1) v += __shfl_down(v, off, 64);
            if (lane == 0) red[r][wave] = v;
        }
        __syncthreads();
        if (t < R) sS[b * R + t] = red[t][0] + red[t][1] + red[t][2] + red[t][3] + bsc[t];
    } else {
        // distance table: 4 distances per block, one 64-lane wave each
        int d = (blk - K2_GEMM - K2_SENT) * 4 + (t >> 6);
        int k = t & 63;
        float v = emb[(size_t)d * D + k];
        #pragma unroll
        for (int r = 0; r < R; ++r) {
            float p = v * Wsc[(size_t)(2 * E + k) * R + r];
            for (int off = 32; off; off >>= 1) p += __shfl_down(p, off, 64);
            if (k == 0) sD[d * R + r] = p;
        }
    }
}

// ---------------------------------------------------------------------------
// K3: sum dotp partials + tanh + rank-R proj (+ fold sS into chem rows).
// grid (2*B*M/4 = 384), block 256: each 64-lane wave handles one entity row.
__global__ void k3(const float* __restrict__ dotp,
                   const float* __restrict__ bc, const float* __restrict__ bd,
                   const float* __restrict__ Wsc, const float* __restrict__ sS,
                   float* __restrict__ sAB) {
    int rid = blockIdx.x * 4 + (threadIdx.x >> 6);
    int lane = threadIdx.x & 63;
    int z = rid / (B * M);
    int b = (rid % (B * M)) / M;
    const float* bias = z ? bd : bc;
    int scoff = z ? E : 0;

    float4 dv = make_float4(0.f, 0.f, 0.f, 0.f);
    #pragma unroll
    for (int hc = 0; hc < HC; ++hc) {
        float4 v = reinterpret_cast<const float4*>(dotp + ((size_t)hc * (2 * B * M) + rid) * E)[lane];
        dv.x += v.x; dv.y += v.y; dv.z += v.z; dv.w += v.w;
    }
    float4 bv = reinterpret_cast<const float4*>(bias)[lane];
    float v0 = tanhf(dv.x + bv.x);
    float v1 = tanhf(dv.y + bv.y);
    float v2 = tanhf(dv.z + bv.z);
    float v3 = tanhf(dv.w + bv.w);

    int e0 = scoff + lane * 4;
    float p[R];
    #pragma unroll
    for (int r = 0; r < R; ++r) {
        p[r] = v0 * Wsc[(size_t)(e0 + 0) * R + r] + v1 * Wsc[(size_t)(e0 + 1) * R + r]
             + v2 * Wsc[(size_t)(e0 + 2) * R + r] + v3 * Wsc[(size_t)(e0 + 3) * R + r];
    }
    #pragma unroll
    for (int r = 0; r < R; ++r) {
        for (int off = 32; off; off >>= 1) p[r] += __shfl_down(p[r], off, 64);
    }
    if (lane == 0) {
        #pragma unroll
        for (int r = 0; r < R; ++r) {
            float add = (z == 0) ? sS[b * R + r] : 0.f;   // fold sent score into chem side
            sAB[(size_t)rid * R + r] = p[r] + add;
        }
    }
}

// ---------------------------------------------------------------------------
// K4: pairwise max, tiled.  grid (12, B), block 256: 8 m-rows x 96 n per block.
__global__ void k4(const int* __restrict__ distance,
                   const float* __restrict__ sAB, const float* __restrict__ validAB,
                   const float* __restrict__ sD, float* __restrict__ out) {
    int g = blockIdx.x, b = blockIdx.y;
    int t = threadIdx.x;
    __shared__ float lB[M * R];
    __shared__ float lD[MAXD * R];
    __shared__ float lA[MT * R];
    __shared__ float lvA[MT], lvB[M];
    __shared__ float red[R][4];

    for (int i = t; i < M * R; i += 256) lB[i] = sAB[((size_t)(B + b)) * M * R + i];
    for (int i = t; i < MAXD * R; i += 256) lD[i] = sD[i];
    if (t < MT * R) lA[t] = sAB[((size_t)b * M + g * MT) * R + t];
    if (t < MT) lvA[t] = validAB[(size_t)b * M + g * MT + t];
    for (int i = t; i < M; i += 256) lvB[i] = validAB[((size_t)B + b) * M + i];
    __syncthreads();

    float mx[R];
    #pragma unroll
    for (int r = 0; r < R; ++r) mx[r] = NEG_INF;

    #pragma unroll
    for (int it = 0; it < (MT * M) / 256; ++it) {
        int idx = it * 256 + t;           // [0, 768)
        int mi = idx / M, n = idx % M;
        int dist = distance[((size_t)b * M + g * MT + mi) * M + n];
        if (lvA[mi] > 0.f && lvB[n] > 0.f && dist >= 0 /*DIST_THRESH*/) {
            #pragma unroll
            for (int r = 0; r < R; ++r)
                mx[r] = fmaxf(mx[r], lA[mi * R + r] + lB[n * R + r] + lD[dist * R + r]);
        }
    }
    int wave = t >> 6, lane = t & 63;
    #pragma unroll
    for (int r = 0; r < R; ++r) {
        float v = mx[r];
        for (int off = 32; off; off >>= 1) v = fmaxf(v, __shfl_down(v, off, 64));
        if (lane == 0) red[r][wave] = v;
    }
    __syncthreads();
    if (t < R) {
        float v = fmaxf(fmaxf(red[t][0], red[t][1]), fmaxf(red[t][2], red[t][3]));
        atomicMaxFloat(out + b * R + t, v);
    }
}

// ---------------------------------------------------------------------------
extern "C" void kernel_launch(void* const* d_in, const int* in_sizes, int n_in,
                              void* d_out, int out_size, void* d_ws, size_t ws_size,
                              hipStream_t stream) {
    const float* node     = (const float*)d_in[0];
    const int*   cmap     = (const int*)  d_in[1];
    const float* cmask    = (const float*)d_in[2];
    const int*   dmap     = (const int*)  d_in[3];
    const float* dmask    = (const float*)d_in[4];
    const int*   distance = (const int*)  d_in[5];
    const float* Wc       = (const float*)d_in[6];
    const float* bc       = (const float*)d_in[7];
    const float* Wd       = (const float*)d_in[8];
    const float* bd       = (const float*)d_in[9];
    const float* Wsc      = (const float*)d_in[10];
    const float* bsc      = (const float*)d_in[11];
    const float* emb      = (const float*)d_in[12];
    float* out = (float*)d_out;

    // workspace layout (floats): total ~10.5 MB
    float* ws      = (float*)d_ws;
    float* part    = ws;                             // NZ*B*H      = 262144
    float* sS      = part + (size_t)NZ * B * H;      // B*R         = 40
    float* sAB     = sS + B * R;                     // 2*B*M*R     = 7680
    float* validAB = sAB + 2 * B * M * R;            // 2*B*M       = 1536
    float* sD      = validAB + 2 * B * M;            // MAXD*R      = 3000
    float* pooled  = sD + MAXD * R;                  // 2*B*M*H     = 786432
    float* dotp    = pooled + (size_t)2 * B * M * H; // HC*2*B*M*E  = 1572864

    hipLaunchKernelGGL(k1, dim3(K1_SENT + K1_POOL), dim3(256), 0, stream,
                       node, cmap, cmask, dmap, dmask, part, pooled, validAB);
    hipLaunchKernelGGL(k2, dim3(K2_GEMM + K2_SENT + K2_DIST), dim3(256), 0, stream,
                       pooled, Wc, Wd, part, Wsc, bsc, emb, dotp, sS, sD, out);
    hipLaunchKernelGGL(k3, dim3(2 * B * M / 4), dim3(256), 0, stream,
                       dotp, bc, bd, Wsc, sS, sAB);
    hipLaunchKernelGGL(k4, dim3(M / MT, B), dim3(256), 0, stream,
                       distance, sAB, validAB, sD, out);
}